// Round 7
// baseline (226.615 us; speedup 1.0000x reference)
//
#include <hip/hip_runtime.h>
#include <stdint.h>

typedef unsigned short u16;
typedef __attribute__((ext_vector_type(8))) short short8;
typedef __attribute__((ext_vector_type(4))) float floatx4;

#define NB 32
#define NC 256
#define NH 32
#define NW 32
#define NO 256
#define NPIX (NH*NW)     // 1024
#define KPIX 9
#define NG 9             // subarrays (groups)
#define RUN 32           // padded run length (per kernel-tap within group)
#define GK (NG*RUN)      // 288 k-slots per group
#define KTOT (NG*GK)     // 2592 real k-slots
#define KSTORE 2624      // + one zero pad run (run 81) so 41 two-run chunks cover 82 runs
#define PADH 34
#define PADSP (PADH*PADH)       // 1156
#define QA_BSTRIDE (PADSP*NC)   // 295936 elems per batch

#define AS1 __attribute__((address_space(1)))
#define AS3 __attribute__((address_space(3)))

// ---------------- fused: per-block absmax slots + zero qa halo borders ----------------
// blocks [0,1024): x-max -> pmax[bid] ; [1024,1088): w-max -> pmax[bid] ; [1088,1376): border zero
__global__ void fused_pre(const float4* __restrict__ x4, int nx4,
                          const float4* __restrict__ w4, int nw4,
                          float* __restrict__ pmax, u16* __restrict__ qa) {
  int bid = blockIdx.x;
  if (bid >= 1088) {
    int zb = bid - 1088;              // 9 blocks per batch
    int b = zb / 9;
    int rem = (zb % 9) * 256 + threadIdx.x;   // need <2112 (132 px * 16 ch-groups)
    if (rem >= 2112) return;
    int pb = rem >> 4, c16 = rem & 15;
    int y, x;
    if (pb < 68) { y = (pb >= 34) ? 33 : 0; x = pb % 34; }
    else { int q = pb - 68; y = 1 + (q >> 1); x = (q & 1) ? 33 : 0; }
    uint4 z; z.x = z.y = z.z = z.w = 0u;
    *(uint4*)(qa + ((size_t)(b * PADH + y) * PADH + x) * NC + c16 * 16) = z;
    return;
  }
  const float4* p; int n4; int nb, b0;
  if (bid < 1024) { p = x4; n4 = nx4; nb = 1024; b0 = bid; }
  else            { p = w4; n4 = nw4; nb = 64;   b0 = bid - 1024; }
  float m = 0.f;
  for (int i = b0 * blockDim.x + threadIdx.x; i < n4; i += nb * blockDim.x) {
    float4 v = p[i];
    m = fmaxf(m, fmaxf(fmaxf(fabsf(v.x), fabsf(v.y)), fmaxf(fabsf(v.z), fabsf(v.w))));
  }
#pragma unroll
  for (int off = 32; off > 0; off >>= 1)
    m = fmaxf(m, __shfl_down(m, off, 64));
  __shared__ float sm[4];
  int lane = threadIdx.x & 63, wv = threadIdx.x >> 6;
  if (lane == 0) sm[wv] = m;
  __syncthreads();
  if (threadIdx.x == 0)
    pmax[bid] = fmaxf(fmaxf(sm[0], sm[1]), fmaxf(sm[2], sm[3]));
}

// helper: reduce the 1024 x-slots and 64 w-slots (any thread count >=256 uses first 256)
__device__ inline void reduce_pmax(const float* pmax, int tid, int nthreads,
                                   float* sred, float& mx_out, float& mw_out) {
  const float4* pf4 = (const float4*)pmax;
  float mx = 0.f, mw = 0.f;
  for (int t = tid; t < 256; t += nthreads) {
    float4 v = pf4[t];
    mx = fmaxf(mx, fmaxf(fmaxf(v.x, v.y), fmaxf(v.z, v.w)));
  }
  if (tid < 16) {
    float4 v = pf4[256 + tid];
    mw = fmaxf(fmaxf(v.x, v.y), fmaxf(v.z, v.w));
  }
#pragma unroll
  for (int off = 32; off > 0; off >>= 1) {
    mx = fmaxf(mx, __shfl_down(mx, off, 64));
    mw = fmaxf(mw, __shfl_down(mw, off, 64));
  }
  int lane = tid & 63, wv = tid >> 6, nw = nthreads >> 6;
  if (lane == 0) { sred[wv] = mx; sred[8 + wv] = mw; }
  __syncthreads();
  mx = sred[0]; mw = sred[8];
  for (int i = 1; i < nw; i++) { mx = fmaxf(mx, sred[i]); mw = fmaxf(mw, sred[8 + i]); }
  mx_out = mx; mw_out = mw;
}

// ---------------- fused quantization: acts (blocks <8192) + weights ----------------
// Same f64 math as all passing rounds; scales re-reduced from per-block slots.
__global__ void fused_quant(const float* __restrict__ x, const float* __restrict__ w,
                            const float* __restrict__ pmax,
                            u16* __restrict__ qa, u16* __restrict__ wq,
                            float* __restrict__ lossp) {
  __shared__ float sred[16];
  float mx, mw;
  reduce_pmax(pmax, threadIdx.x, 256, sred, mx, mw);
  int bid = blockIdx.x;
  if (bid < 8192) {
    __shared__ u16 t[32][33];
    double s = (double)mx + 1e-12;
    double inv = 255.0 / s;
    int tx = threadIdx.x & 31, ty = threadIdx.x >> 5;
    int ct = bid & 7, y = (bid >> 3) & 31, b = bid >> 8;
#pragma unroll
    for (int j = 0; j < 4; j++) {
      int cl = ty + j * 8;
      float v = x[(((size_t)b * NC + ct * 32 + cl) * NH + y) * NW + tx];
      double q = rint((double)v * inv);
      float qf = (float)q;                       // integer, |q|<=255: exact in bf16
      t[cl][tx] = (u16)(__float_as_uint(qf) >> 16);
    }
    __syncthreads();
#pragma unroll
    for (int j = 0; j < 4; j++) {
      int xq = ty + j * 8;
      qa[((size_t)(b * PADH + y + 1) * PADH + (xq + 1)) * NC + ct * 32 + tx] = t[tx][xq];
    }
    return;
  }
  // ---- weights: 2624 blocks cover NO*KSTORE = 671744 slots ----
  double s = (double)mw + 1e-12;
  double inv = 15.0 / s;
  int idx = (bid - 8192) * blockDim.x + threadIdx.x;
  if (idx == 0) *lossp = 0.0f;                  // a_loss output
  if (idx >= NO * KSTORE) return;
  int o = idx / KSTORE, kk = idx % KSTORE;
  float val = 0.f;
  if (kk < KTOT) {
    int g = kk / GK, rem = kk % GK;
    int r = rem / RUN, j = rem % RUN;
    int clo = (256 * g - r + 8) / 9;
    int chi = (256 * (g + 1) - r + 8) / 9; if (chi > NC) chi = NC;
    int cst = clo & ~3;
    int c = cst + j;
    if (c >= clo && c < chi) {
      float wv = w[((size_t)o * NC + c) * KPIX + r];
      val = (float)rint((double)wv * inv);
    }
  }
  wq[idx] = (u16)(__float_as_uint(val) >> 16);
}

// ---------------- fused GEMM + per-group ADC, cross-chunk double-buffered ----------------
// 128x64 block tile, 128 threads (2 waves x 64x64). 41 chunks of 2 runs (64-K).
// LDS 48 KB (2 bufs) -> 3 blocks/CU. Loads for chunk c+1 issue before compute(c);
// raw s_barrier + s_waitcnt vmcnt(12) keeps prefetch in flight across the barrier
// (no vmcnt(0) drain). Grid (4,256): consecutive blocks share the A-tile (L2 reuse).
__global__ __launch_bounds__(128, 2) void gemm_adc(const u16* __restrict__ qa,
                                                   const u16* __restrict__ wq,
                                                   const float* __restrict__ pmax,
                                                   float* __restrict__ out) {
  __shared__ u16 lA[2 * 2 * 128 * RUN];   // 2 bufs x (2 runs x 128 x 32) = 32 KB
  __shared__ u16 lB[2 * 2 * 64 * RUN];    // 16 KB
  __shared__ float sred[16];
  const int tid = threadIdx.x;
  float mx, mw;
  reduce_pmax(pmax, tid, 128, sred, mx, mw);

  const int nblk = blockIdx.x, mblk = blockIdx.y;
  const int b = mblk >> 3;
  const int p0 = (mblk & 7) * 128;        // pixel base (4 image rows of 32)
  const int n0 = nblk * 64;
  const int lane = tid & 63, wv = tid >> 6;
  const int fm = lane & 15, fq = lane >> 4;
  const int swz = (fq + ((fm >> 1) & 3)) & 3;

  double sa = (double)mx + 1e-12;
  double sw = (double)mw + 1e-12;
  double Sstep = sa * sw * 0.999 / 459.0;   // I/step = intsum * Sstep

  // staging: per run, A = 4 quarters (rows (tid>>2)+ii*32), B = 2 halves; j' = tid&3
  // global k-word jsrc = ((tid&3) - ((tid>>3)&3)) & 3  (source-side bank swizzle)
  const int r0 = tid >> 2;
  const int jsrc = ((tid & 3) - ((tid >> 3) & 3)) & 3;
  const u16* Abase = qa + (size_t)b * QA_BSTRIDE
                     + (((p0 >> 5) + 1) * PADH + (r0 + 1)) * NC + jsrc * 8;
  const u16* Bbase = wq + (size_t)(n0 + r0) * KSTORE + jsrc * 8;

  auto issue = [&](int c, int buf) {
#pragma unroll
    for (int rl = 0; rl < 2; rl++) {
      int r = 2 * c + rl;                 // 0..81 (81 = zero pad run)
      int ra = (r >= 81) ? 80 : r;        // A address clamp for the pad run
      int g = ra / 9, rr = ra % 9;
      int cst = ((256 * g - rr + 8) / 9) & ~3;
      int offA = ((rr / 3 - 1) * PADH + (rr % 3 - 1)) * NC + cst;
      int offB = r * RUN;
      u16* Ad = &lA[buf * 8192 + rl * 4096 + tid * 8];
      u16* Bd = &lB[buf * 4096 + rl * 2048 + tid * 8];
#pragma unroll
      for (int ii = 0; ii < 4; ii++)
        __builtin_amdgcn_global_load_lds((const AS1 void*)(Abase + offA + ii * (PADH * NC)),
                                         (AS3 void*)(Ad + ii * 1024), 16, 0, 0);
#pragma unroll
      for (int ii = 0; ii < 2; ii++)
        __builtin_amdgcn_global_load_lds((const AS1 void*)(Bbase + offB + ii * 32 * KSTORE),
                                         (AS3 void*)(Bd + ii * 1024), 16, 0, 0);
    }
  };

  floatx4 acc[4][4];
  float tot[4][4][4];
#pragma unroll
  for (int mi = 0; mi < 4; mi++)
#pragma unroll
    for (int ni = 0; ni < 4; ni++)
#pragma unroll
      for (int rr = 0; rr < 4; rr++) { acc[mi][ni][rr] = 0.f; tot[mi][ni][rr] = 0.f; }

  issue(0, 0);
#pragma unroll 1
  for (int c = 0; c < 41; c++) {
    if (c < 40) {
      issue(c + 1, (c + 1) & 1);
      asm volatile("s_waitcnt vmcnt(12)" ::: "memory");   // chunk-c loads done, c+1 in flight
    } else {
      asm volatile("s_waitcnt vmcnt(0)" ::: "memory");
    }
    __builtin_amdgcn_s_barrier();
    asm volatile("" ::: "memory");
    const int buf = c & 1;
#pragma unroll
    for (int rl = 0; rl < 2; rl++) {
      const u16* pA = &lA[buf * 8192 + rl * 4096];
      const u16* pB = &lB[buf * 4096 + rl * 2048];
      short8 afr[4], bfr[4];
#pragma unroll
      for (int mi = 0; mi < 4; mi++)
        afr[mi] = *(const short8*)&pA[(wv * 64 + mi * 16 + fm) * RUN + swz * 8];
#pragma unroll
      for (int ni = 0; ni < 4; ni++)
        bfr[ni] = *(const short8*)&pB[(ni * 16 + fm) * RUN + swz * 8];
#pragma unroll
      for (int mi = 0; mi < 4; mi++)
#pragma unroll
        for (int ni = 0; ni < 4; ni++)
          acc[mi][ni] = __builtin_amdgcn_mfma_f32_16x16x32_bf16(afr[mi], bfr[ni], acc[mi][ni], 0, 0, 0);
      int r = 2 * c + rl;
      if (r % 9 == 8) {
        // ---- per-group ADC fold (f64 mul+rint EXACTLY as the passing kernels) ----
#pragma unroll
        for (int mi = 0; mi < 4; mi++)
#pragma unroll
          for (int ni = 0; ni < 4; ni++)
#pragma unroll
            for (int rr = 0; rr < 4; rr++) {
              double d = (double)acc[mi][ni][rr] * Sstep;
              float tf = (float)rint(d);
              tf = fminf(fmaxf(tf, -128.f), 127.f);
              tot[mi][ni][rr] += tf;
              acc[mi][ni][rr] = 0.f;
            }
      }
    }
    asm volatile("" ::: "memory");
    __builtin_amdgcn_s_barrier();       // all waves done with buf before it is re-filled
    asm volatile("" ::: "memory");
  }
  // ---- epilogue ----
#pragma unroll
  for (int mi = 0; mi < 4; mi++)
#pragma unroll
    for (int ni = 0; ni < 4; ni++) {
      int o = n0 + ni * 16 + fm;
      int p = p0 + wv * 64 + mi * 16 + fq * 4;
      float4 o4;
      o4.x = tot[mi][ni][0] * 1e-3f;
      o4.y = tot[mi][ni][1] * 1e-3f;
      o4.z = tot[mi][ni][2] * 1e-3f;
      o4.w = tot[mi][ni][3] * 1e-3f;
      *(float4*)(out + ((size_t)(b * NO + o)) * NPIX + p) = o4;
    }
}

extern "C" void kernel_launch(void* const* d_in, const int* in_sizes, int n_in,
                              void* d_out, int out_size, void* d_ws, size_t ws_size,
                              hipStream_t stream) {
  const float* x = (const float*)d_in[0];
  const float* w = (const float*)d_in[1];
  float* out = (float*)d_out;

  float* pmax = (float*)d_ws;                                // 1088 slots
  u16* qa = (u16*)((char*)d_ws + 8192);                      // padded acts: 18,939,904 B
  u16* wq = (u16*)((char*)d_ws + 8192 + 18939904 + 8192);    // weights: 256*2624*2 B

  fused_pre<<<1376, 256, 0, stream>>>((const float4*)x, (NB * NC * NH * NW) / 4,
                                      (const float4*)w, (NO * NC * KPIX) / 4,
                                      pmax, qa);
  fused_quant<<<8192 + 2624, 256, 0, stream>>>(x, w, pmax, qa, wq, out + (out_size - 1));
  gemm_adc<<<dim3(4, 256), 128, 0, stream>>>(qa, wq, pmax, out);
}

// Round 8
// 189.473 us; speedup vs baseline: 1.1960x; 1.1960x over previous
//
#include <hip/hip_runtime.h>
#include <stdint.h>

typedef unsigned short u16;
typedef __attribute__((ext_vector_type(8))) short short8;
typedef __attribute__((ext_vector_type(4))) float floatx4;

#define NB 32
#define NC 256
#define NH 32
#define NW 32
#define NO 256
#define NPIX (NH*NW)     // 1024
#define KPIX 9
#define NG 9             // subarrays (groups)
#define RUN 32           // padded run length (per kernel-tap within group)
#define GK (NG*RUN)      // 288 k-slots per group
#define KTOT (NG*GK)     // 2592 real k-slots
#define KSTORE 2624      // + one zero pad run (run 81) so 41 two-run chunks cover 82 runs
#define PADH 34
#define PADSP (PADH*PADH)       // 1156
#define QA_BSTRIDE (PADSP*NC)   // 295936 elems per batch

#define AS1 __attribute__((address_space(1)))
#define AS3 __attribute__((address_space(3)))

// ---------------- fused: per-block absmax slots + zero qa halo borders ----------------
__global__ void fused_pre(const float4* __restrict__ x4, int nx4,
                          const float4* __restrict__ w4, int nw4,
                          float* __restrict__ pmax, u16* __restrict__ qa) {
  int bid = blockIdx.x;
  if (bid >= 1088) {
    int zb = bid - 1088;              // 9 blocks per batch
    int b = zb / 9;
    int rem = (zb % 9) * 256 + threadIdx.x;   // need <2112 (132 px * 16 ch-groups)
    if (rem >= 2112) return;
    int pb = rem >> 4, c16 = rem & 15;
    int y, x;
    if (pb < 68) { y = (pb >= 34) ? 33 : 0; x = pb % 34; }
    else { int q = pb - 68; y = 1 + (q >> 1); x = (q & 1) ? 33 : 0; }
    uint4 z; z.x = z.y = z.z = z.w = 0u;
    *(uint4*)(qa + ((size_t)(b * PADH + y) * PADH + x) * NC + c16 * 16) = z;
    return;
  }
  const float4* p; int n4; int nb, b0;
  if (bid < 1024) { p = x4; n4 = nx4; nb = 1024; b0 = bid; }
  else            { p = w4; n4 = nw4; nb = 64;   b0 = bid - 1024; }
  float m = 0.f;
  for (int i = b0 * blockDim.x + threadIdx.x; i < n4; i += nb * blockDim.x) {
    float4 v = p[i];
    m = fmaxf(m, fmaxf(fmaxf(fabsf(v.x), fabsf(v.y)), fmaxf(fabsf(v.z), fabsf(v.w))));
  }
#pragma unroll
  for (int off = 32; off > 0; off >>= 1)
    m = fmaxf(m, __shfl_down(m, off, 64));
  __shared__ float sm[4];
  int lane = threadIdx.x & 63, wv = threadIdx.x >> 6;
  if (lane == 0) sm[wv] = m;
  __syncthreads();
  if (threadIdx.x == 0)
    pmax[bid] = fmaxf(fmaxf(sm[0], sm[1]), fmaxf(sm[2], sm[3]));
}

// helper: reduce the 1024 x-slots and 64 w-slots
__device__ inline void reduce_pmax(const float* pmax, int tid, int nthreads,
                                   float* sred, float& mx_out, float& mw_out) {
  const float4* pf4 = (const float4*)pmax;
  float mx = 0.f, mw = 0.f;
  for (int t = tid; t < 256; t += nthreads) {
    float4 v = pf4[t];
    mx = fmaxf(mx, fmaxf(fmaxf(v.x, v.y), fmaxf(v.z, v.w)));
  }
  if (tid < 16) {
    float4 v = pf4[256 + tid];
    mw = fmaxf(fmaxf(v.x, v.y), fmaxf(v.z, v.w));
  }
#pragma unroll
  for (int off = 32; off > 0; off >>= 1) {
    mx = fmaxf(mx, __shfl_down(mx, off, 64));
    mw = fmaxf(mw, __shfl_down(mw, off, 64));
  }
  int lane = tid & 63, wv = tid >> 6, nw = nthreads >> 6;
  if (lane == 0) { sred[wv] = mx; sred[8 + wv] = mw; }
  __syncthreads();
  mx = sred[0]; mw = sred[8];
  for (int i = 1; i < nw; i++) { mx = fmaxf(mx, sred[i]); mw = fmaxf(mw, sred[8 + i]); }
  mx_out = mx; mw_out = mw;
}

// ---------------- fused quantization: acts (blocks <8192) + weights ----------------
__global__ void fused_quant(const float* __restrict__ x, const float* __restrict__ w,
                            const float* __restrict__ pmax,
                            u16* __restrict__ qa, u16* __restrict__ wq,
                            float* __restrict__ lossp) {
  __shared__ float sred[16];
  float mx, mw;
  reduce_pmax(pmax, threadIdx.x, 256, sred, mx, mw);
  int bid = blockIdx.x;
  if (bid < 8192) {
    __shared__ u16 t[32][33];
    double s = (double)mx + 1e-12;
    double inv = 255.0 / s;
    int tx = threadIdx.x & 31, ty = threadIdx.x >> 5;
    int ct = bid & 7, y = (bid >> 3) & 31, b = bid >> 8;
#pragma unroll
    for (int j = 0; j < 4; j++) {
      int cl = ty + j * 8;
      float v = x[(((size_t)b * NC + ct * 32 + cl) * NH + y) * NW + tx];
      double q = rint((double)v * inv);
      float qf = (float)q;                       // integer, |q|<=255: exact in bf16
      t[cl][tx] = (u16)(__float_as_uint(qf) >> 16);
    }
    __syncthreads();
#pragma unroll
    for (int j = 0; j < 4; j++) {
      int xq = ty + j * 8;
      qa[((size_t)(b * PADH + y + 1) * PADH + (xq + 1)) * NC + ct * 32 + tx] = t[tx][xq];
    }
    return;
  }
  // ---- weights: 2624 blocks cover NO*KSTORE = 671744 slots ----
  double s = (double)mw + 1e-12;
  double inv = 15.0 / s;
  int idx = (bid - 8192) * blockDim.x + threadIdx.x;
  if (idx == 0) *lossp = 0.0f;                  // a_loss output
  if (idx >= NO * KSTORE) return;
  int o = idx / KSTORE, kk = idx % KSTORE;
  float val = 0.f;
  if (kk < KTOT) {
    int g = kk / GK, rem = kk % GK;
    int r = rem / RUN, j = rem % RUN;
    int clo = (256 * g - r + 8) / 9;
    int chi = (256 * (g + 1) - r + 8) / 9; if (chi > NC) chi = NC;
    int cst = clo & ~3;
    int c = cst + j;
    if (c >= clo && c < chi) {
      float wv = w[((size_t)o * NC + c) * KPIX + r];
      val = (float)rint((double)wv * inv);
    }
  }
  wq[idx] = (u16)(__float_as_uint(val) >> 16);
}

// ---------------- fused GEMM + per-group ADC ----------------
// 256x128 block tile, 512 threads (8 waves x 64x64 tiles), grid (128,2)=256 blocks
// = 1 block/CU. Staged bytes halved vs 128x64 (the ~13 TB/s staging ceiling is the
// binding constraint). 2-run 64-K chunks, R6-proven __syncthreads structure,
// source-side bank swizzle (conflict-free, verified R4).
__global__ __launch_bounds__(512, 2) void gemm_adc(const u16* __restrict__ qa,
                                                   const u16* __restrict__ wq,
                                                   const float* __restrict__ pmax,
                                                   float* __restrict__ out) {
  __shared__ u16 lA[2 * 256 * RUN];   // 2 runs x 256 rows x 32k = 32 KB
  __shared__ u16 lB[2 * 128 * RUN];   // 16 KB
  __shared__ float sred[16];
  const int tid = threadIdx.x;
  float mx, mw;
  reduce_pmax(pmax, tid, 512, sred, mx, mw);

  const int mblk = blockIdx.x, nblk = blockIdx.y;
  const int b = mblk >> 2;                 // 4 m-blocks per image
  const int ybase = (mblk & 3) * 8;        // 8 image rows per block
  const int pimg0 = (mblk & 3) * 256;
  const int n0 = nblk * 128;
  const int lane = tid & 63, wv = tid >> 6;
  const int wm = (wv & 3) * 64, wn = (wv >> 2) * 64;
  const int fm = lane & 15, fq = lane >> 4;
  const int swz = (fq + ((fm >> 1) & 3)) & 3;

  double sa = (double)mx + 1e-12;
  double sw = (double)mw + 1e-12;
  double Sstep = sa * sw * 0.999 / 459.0;   // I/step = intsum * Sstep

  // staging: A slot s = tid + i*512 (i=0,1): row = s>>2 in [0,256), j' = s&3
  // B slot: row = tid>>2 in [0,128), j' = tid&3
  // global k-word jsrc = ((tid&3) - ((tid>>3)&3)) & 3  (same for both A slots: 512>>3 = 64 = 0 mod 4)
  const int jsrc = ((tid & 3) - ((tid >> 3) & 3)) & 3;
  const u16* Ab[2];
#pragma unroll
  for (int i = 0; i < 2; i++) {
    int row = (tid >> 2) + i * 128;
    int y = row >> 5, x = row & 31;
    Ab[i] = qa + (size_t)b * QA_BSTRIDE
            + ((ybase + y + 1) * PADH + (x + 1)) * NC + jsrc * 8;
  }
  const u16* Bb = wq + (size_t)(n0 + (tid >> 2)) * KSTORE + jsrc * 8;

  floatx4 acc[4][4];
  float tot[4][4][4];
#pragma unroll
  for (int mi = 0; mi < 4; mi++)
#pragma unroll
    for (int ni = 0; ni < 4; ni++)
#pragma unroll
      for (int rr = 0; rr < 4; rr++) { acc[mi][ni][rr] = 0.f; tot[mi][ni][rr] = 0.f; }

#pragma unroll 1
  for (int c = 0; c < 41; c++) {
    // ---- stage 2 runs (64-K) ----
#pragma unroll
    for (int rl = 0; rl < 2; rl++) {
      int r = 2 * c + rl;                 // 0..81 (81 = zero pad run)
      int ra = (r >= 81) ? 80 : r;        // A address clamp for the pad run (B is real zeros)
      int g = ra / 9, rr = ra % 9;
      int cst = ((256 * g - rr + 8) / 9) & ~3;
      int offA = ((rr / 3 - 1) * PADH + (rr % 3 - 1)) * NC + cst;
      int offB = r * RUN;
#pragma unroll
      for (int i = 0; i < 2; i++)
        __builtin_amdgcn_global_load_lds((const AS1 void*)(Ab[i] + offA),
                                         (AS3 void*)&lA[rl * 8192 + (tid + i * 512) * 8], 16, 0, 0);
      __builtin_amdgcn_global_load_lds((const AS1 void*)(Bb + offB),
                                       (AS3 void*)&lB[rl * 4096 + tid * 8], 16, 0, 0);
    }
    __syncthreads();
    // ---- compute 2 runs x 16 MFMA per wave ----
#pragma unroll
    for (int rl = 0; rl < 2; rl++) {
      const u16* pA = &lA[rl * 8192];
      const u16* pB = &lB[rl * 4096];
      short8 afr[4], bfr[4];
#pragma unroll
      for (int mi = 0; mi < 4; mi++)
        afr[mi] = *(const short8*)&pA[(wm + mi * 16 + fm) * RUN + swz * 8];
#pragma unroll
      for (int ni = 0; ni < 4; ni++)
        bfr[ni] = *(const short8*)&pB[(wn + ni * 16 + fm) * RUN + swz * 8];
#pragma unroll
      for (int mi = 0; mi < 4; mi++)
#pragma unroll
        for (int ni = 0; ni < 4; ni++)
          acc[mi][ni] = __builtin_amdgcn_mfma_f32_16x16x32_bf16(afr[mi], bfr[ni], acc[mi][ni], 0, 0, 0);
      int r = 2 * c + rl;
      if (r % 9 == 8) {
        // ---- per-group ADC fold (f64 mul+rint EXACTLY as the passing kernels) ----
#pragma unroll
        for (int mi = 0; mi < 4; mi++)
#pragma unroll
          for (int ni = 0; ni < 4; ni++)
#pragma unroll
            for (int rr = 0; rr < 4; rr++) {
              double d = (double)acc[mi][ni][rr] * Sstep;
              float tf = (float)rint(d);
              tf = fminf(fmaxf(tf, -128.f), 127.f);
              tot[mi][ni][rr] += tf;
              acc[mi][ni][rr] = 0.f;
            }
      }
    }
    __syncthreads();     // protect LDS before next chunk's refill
  }
  // ---- epilogue ----
#pragma unroll
  for (int mi = 0; mi < 4; mi++)
#pragma unroll
    for (int ni = 0; ni < 4; ni++) {
      int o = n0 + wn + ni * 16 + fm;
      int p = pimg0 + wm + mi * 16 + fq * 4;
      float4 o4;
      o4.x = tot[mi][ni][0] * 1e-3f;
      o4.y = tot[mi][ni][1] * 1e-3f;
      o4.z = tot[mi][ni][2] * 1e-3f;
      o4.w = tot[mi][ni][3] * 1e-3f;
      *(float4*)(out + ((size_t)(b * NO + o)) * NPIX + p) = o4;
    }
}

extern "C" void kernel_launch(void* const* d_in, const int* in_sizes, int n_in,
                              void* d_out, int out_size, void* d_ws, size_t ws_size,
                              hipStream_t stream) {
  const float* x = (const float*)d_in[0];
  const float* w = (const float*)d_in[1];
  float* out = (float*)d_out;

  float* pmax = (float*)d_ws;                                // 1088 slots
  u16* qa = (u16*)((char*)d_ws + 8192);                      // padded acts: 18,939,904 B
  u16* wq = (u16*)((char*)d_ws + 8192 + 18939904 + 8192);    // weights: 256*2624*2 B

  fused_pre<<<1376, 256, 0, stream>>>((const float4*)x, (NB * NC * NH * NW) / 4,
                                      (const float4*)w, (NO * NC * KPIX) / 4,
                                      pmax, qa);
  fused_quant<<<8192 + 2624, 256, 0, stream>>>(x, w, pmax, qa, wq, out + (out_size - 1));
  gemm_adc<<<dim3(128, 2), 512, 0, stream>>>(qa, wq, pmax, out);
}